// Round 8
// baseline (2812.444 us; speedup 1.0000x reference)
//
#include <hip/hip_runtime.h>
#include <hip/hip_bf16.h>
#include <cstdint>

#define BB 256
#define TT 1024
#define HH 128
#define OO 128

typedef __attribute__((ext_vector_type(8))) short short8v;
typedef __attribute__((ext_vector_type(4))) float f32x4;

__device__ __forceinline__ float sigmoidf_(float x) { return 1.f / (1.f + expf(-x)); }

__device__ __forceinline__ short f2bf(float x) {
  unsigned u = __float_as_uint(x);
  u = u + 0x7fffu + ((u >> 16) & 1u);
  return (short)(u >> 16);
}
__device__ __forceinline__ float bf2f(short s) {
  return __uint_as_float(((unsigned)(unsigned short)s) << 16);
}
__device__ __forceinline__ void splitA(const float* p, short8v& hi, short8v& lo) {
  float4 a = *(const float4*)p;
  float4 b = *(const float4*)(p + 4);
  float v[8] = {a.x, a.y, a.z, a.w, b.x, b.y, b.z, b.w};
  #pragma unroll
  for (int i = 0; i < 8; ++i) {
    short h = f2bf(v[i]);
    hi[i] = h;
    lo[i] = f2bf(v[i] - bf2f(h));
  }
}

// ---------------------------------------------------------------------------
// K0: weight prep -> hi/lo bf16 MFMA-B fragment-linear layout.
// mats: 0=Wgx 1=Wgh 2=Wz1 3=Wz3 4=Wr1 5=Wr3 6=Wh1 7=Wh3
// ---------------------------------------------------------------------------
__global__ __launch_bounds__(256) void k0_wprep(
    const float* __restrict__ Wz, const float* __restrict__ Wr,
    const float* __restrict__ Wh, const float* __restrict__ Wgx,
    const float* __restrict__ Wgh, short* __restrict__ WFRAG) {
  const int mat = blockIdx.x;
  const float* src;
  int koff;
  switch (mat) {
    case 0: src = Wgx; koff = 0; break;
    case 1: src = Wgh; koff = 0; break;
    case 2: src = Wz;  koff = 0; break;
    case 3: src = Wz;  koff = 256; break;
    case 4: src = Wr;  koff = 0; break;
    case 5: src = Wr;  koff = 256; break;
    case 6: src = Wh;  koff = 0; break;
    default: src = Wh; koff = 256; break;
  }
  short* hi = WFRAG + (size_t)mat * 32768;
  short* lo = hi + 16384;
  for (int e = threadIdx.x; e < 16384; e += 256) {
    int i = e & 7, ln = (e >> 3) & 63, tile = e >> 9;
    int kt = tile >> 3, nt = tile & 7;
    int k = kt * 32 + (ln >> 4) * 8 + i;
    int n = nt * 16 + (ln & 15);
    float w = src[(size_t)(koff + k) * HH + n];
    short h = f2bf(w);
    hi[e] = h;
    lo[e] = f2bf(w - bf2f(h));
  }
}

// ---------------------------------------------------------------------------
// K1a: x_mean + init carry/hstate. carry: 0=xlast 1=delta_prev 2=tprev 3=m_prev
// ---------------------------------------------------------------------------
__global__ __launch_bounds__(512) void k1a_mean(
    const float* __restrict__ C, const float* __restrict__ mask,
    float* __restrict__ xmean, float* __restrict__ carry,
    float* __restrict__ hstate) {
  const int b = blockIdx.x;
  const int h = threadIdx.x & (HH - 1);
  const int s = threadIdx.x >> 7;
  __shared__ float ssum[4][HH], scnt[4][HH];
  const float* mptr = mask + (size_t)b * TT * HH + h;
  float sum = 0.f, cnt = 0.f;
  for (int t = s; t < TT; t += 4) {
    float m = mptr[(size_t)t * HH];
    sum = fmaf(m, C[t * HH + h], sum);
    cnt += m;
  }
  ssum[s][h] = sum; scnt[s][h] = cnt;
  __syncthreads();
  if (s == 0) {
    float S = (ssum[0][h] + ssum[1][h]) + (ssum[2][h] + ssum[3][h]);
    float N = (scnt[0][h] + scnt[1][h]) + (scnt[2][h] + scnt[3][h]);
    float xm = S / fmaxf(N, 1.f);
    const size_t bh = (size_t)b * HH + h;
    const size_t BH = (size_t)BB * HH;
    xmean[bh] = xm;
    carry[0 * BH + bh] = xm;
    carry[1 * BH + bh] = 0.f;
    carry[2 * BH + bh] = 0.f;
    carry[3 * BH + bh] = 1.f;
    hstate[bh] = 0.f;
  }
}

// ---------------------------------------------------------------------------
// K1b: per-(b,h) scan for one chunk -> delta_c, xlastp_c
// ---------------------------------------------------------------------------
__global__ __launch_bounds__(128) void k1b_scan(
    const float* __restrict__ C, const float* __restrict__ tarr,
    const float* __restrict__ mask, float* __restrict__ carry,
    float* __restrict__ delta_c, float* __restrict__ xlastp_c,
    int t0, int TC) {
  const int b = blockIdx.x;
  const int h = threadIdx.x;
  const size_t bh = (size_t)b * HH + h;
  const size_t BH = (size_t)BB * HH;
  float xl = carry[0 * BH + bh];
  float dp = carry[1 * BH + bh];
  float tprev = carry[2 * BH + bh];
  float mp = carry[3 * BH + bh];
  const float* trow = tarr + (size_t)b * TT;
  const float* mptr = mask + ((size_t)b * TT + t0) * HH + h;
  const size_t cbase = (size_t)b * TC * HH + h;
  for (int tl = 0; tl < TC; ++tl) {
    const int t = t0 + tl;
    float tc = trow[t];
    float dt = (t == 0) ? 0.f : (tc - tprev);
    float d = dt + (1.f - mp) * dp;
    delta_c[cbase + (size_t)tl * HH] = d;
    xlastp_c[cbase + (size_t)tl * HH] = xl;
    float m = mptr[(size_t)tl * HH];
    float xv = C[t * HH + h];
    xl = m * xv + (1.f - m) * xl;
    mp = m; dp = d; tprev = tc;
  }
  carry[0 * BH + bh] = xl;
  carry[1 * BH + bh] = dp;
  carry[2 * BH + bh] = tprev;
  carry[3 * BH + bh] = mp;
}

// ---------------------------------------------------------------------------
// K2: split-bf16 MFMA precompute. SB stream-major:
// SB[g][s][128], s: 0=az 1=ar 2=ah 3=gh.
// ---------------------------------------------------------------------------
__global__ __launch_bounds__(256) void k2_mfma(
    const float* __restrict__ C, const float* __restrict__ mask,
    const float* __restrict__ bz, const float* __restrict__ br,
    const float* __restrict__ bh_, const float* __restrict__ bgx,
    const float* __restrict__ bgh, const float* __restrict__ xmean,
    const float* __restrict__ delta, const float* __restrict__ xlastp,
    const short* __restrict__ WFRAG, float* __restrict__ xh_ws,
    float* __restrict__ SB, int t0, int TC, int l2tc) {
  __shared__ short sW[32768];
  const int tid = threadIdx.x;
  const int lane = tid & 63;
  const int wv = tid >> 6;
  const long row0 = (long)blockIdx.x * 128;
  const int lcol = lane & 15;
  const int lkg = lane >> 4;

  #define STAGE(matIdx)                                                      \
    {                                                                        \
      const int4* gsrc = (const int4*)(WFRAG + (size_t)(matIdx) * 32768);    \
      int4* gdst = (int4*)sW;                                                \
      _Pragma("unroll")                                                      \
      for (int i_ = 0; i_ < 16; ++i_) gdst[tid + i_ * 256] = gsrc[tid + i_ * 256]; \
    }
  #define BFRAG(kt, nt, plane) \
    (*(const short8v*)&sW[(plane) * 16384 + (((kt) * 8 + (nt)) * 64 + lane) * 8])

  // ================= Phase A =================
  f32x4 accGX[2][8], accGH[2][8];
  const f32x4 zero4 = {0.f, 0.f, 0.f, 0.f};
  #pragma unroll
  for (int mt = 0; mt < 2; ++mt)
    #pragma unroll
    for (int nt = 0; nt < 8; ++nt) { accGX[mt][nt] = zero4; accGH[mt][nt] = zero4; }

  STAGE(0);
  __syncthreads();
  #pragma unroll
  for (int kt = 0; kt < 4; ++kt) {
    short8v ahi[2], alo[2];
    #pragma unroll
    for (int mt = 0; mt < 2; ++mt) {
      long r = row0 + (wv * 2 + mt) * 16 + lcol;
      splitA(delta + r * HH + kt * 32 + lkg * 8, ahi[mt], alo[mt]);
    }
    #pragma unroll
    for (int nt = 0; nt < 8; ++nt) {
      short8v bhi = BFRAG(kt, nt, 0), blo = BFRAG(kt, nt, 1);
      #pragma unroll
      for (int mt = 0; mt < 2; ++mt) {
        accGX[mt][nt] = __builtin_amdgcn_mfma_f32_16x16x32_bf16(ahi[mt], bhi, accGX[mt][nt], 0, 0, 0);
        accGX[mt][nt] = __builtin_amdgcn_mfma_f32_16x16x32_bf16(ahi[mt], blo, accGX[mt][nt], 0, 0, 0);
        accGX[mt][nt] = __builtin_amdgcn_mfma_f32_16x16x32_bf16(alo[mt], bhi, accGX[mt][nt], 0, 0, 0);
      }
    }
  }
  __syncthreads();
  STAGE(1);
  __syncthreads();
  #pragma unroll
  for (int kt = 0; kt < 4; ++kt) {
    short8v ahi[2], alo[2];
    #pragma unroll
    for (int mt = 0; mt < 2; ++mt) {
      long r = row0 + (wv * 2 + mt) * 16 + lcol;
      splitA(delta + r * HH + kt * 32 + lkg * 8, ahi[mt], alo[mt]);
    }
    #pragma unroll
    for (int nt = 0; nt < 8; ++nt) {
      short8v bhi = BFRAG(kt, nt, 0), blo = BFRAG(kt, nt, 1);
      #pragma unroll
      for (int mt = 0; mt < 2; ++mt) {
        accGH[mt][nt] = __builtin_amdgcn_mfma_f32_16x16x32_bf16(ahi[mt], bhi, accGH[mt][nt], 0, 0, 0);
        accGH[mt][nt] = __builtin_amdgcn_mfma_f32_16x16x32_bf16(ahi[mt], blo, accGH[mt][nt], 0, 0, 0);
        accGH[mt][nt] = __builtin_amdgcn_mfma_f32_16x16x32_bf16(alo[mt], bhi, accGH[mt][nt], 0, 0, 0);
      }
    }
  }
  __syncthreads();

  #pragma unroll
  for (int mt = 0; mt < 2; ++mt) {
    #pragma unroll
    for (int r = 0; r < 4; ++r) {
      const int mrow = (wv * 2 + mt) * 16 + lkg * 4 + r;
      const long g = row0 + mrow;
      const int b = (int)(g >> l2tc);
      const int tl = (int)(g & (TC - 1));
      const int tg = t0 + tl;
      #pragma unroll
      for (int nt = 0; nt < 8; ++nt) {
        const int j = nt * 16 + lcol;
        float gx = expf(-fmaxf(accGX[mt][nt][r] + bgx[j], 0.f));
        float gh = expf(-fmaxf(accGH[mt][nt][r] + bgh[j], 0.f));
        SB[g * 512 + 384 + j] = gh;
        float mk = mask[((size_t)b * TT + tg) * HH + j];
        float xl = xlastp[g * HH + j];
        float xmn = xmean[(size_t)b * HH + j];
        float xv = C[(size_t)tg * HH + j];
        xh_ws[g * HH + j] = mk * xv + (1.f - mk) * (gx * xl + (1.f - gx) * xmn);
      }
    }
  }
  __threadfence_block();
  __syncthreads();

  // ================= Phase B =================
  short8v mfr[2][4];
  #pragma unroll
  for (int mt = 0; mt < 2; ++mt) {
    long r = row0 + (wv * 2 + mt) * 16 + lcol;
    const int b = (int)(r >> l2tc);
    const int tl = (int)(r & (TC - 1));
    const float* mrow = mask + ((size_t)b * TT + t0 + tl) * HH;
    #pragma unroll
    for (int kt = 0; kt < 4; ++kt) {
      float4 p = *(const float4*)(mrow + kt * 32 + lkg * 8);
      float4 q = *(const float4*)(mrow + kt * 32 + lkg * 8 + 4);
      float v[8] = {p.x, p.y, p.z, p.w, q.x, q.y, q.z, q.w};
      #pragma unroll
      for (int i = 0; i < 8; ++i) mfr[mt][kt][i] = f2bf(v[i]);
    }
  }

  #pragma unroll 1
  for (int mat = 0; mat < 3; ++mat) {
    f32x4 acc[2][8];
    #pragma unroll
    for (int mt = 0; mt < 2; ++mt)
      #pragma unroll
      for (int nt = 0; nt < 8; ++nt) acc[mt][nt] = zero4;

    STAGE(2 + mat * 2);
    __syncthreads();
    #pragma unroll
    for (int kt = 0; kt < 4; ++kt) {
      short8v ahi[2], alo[2];
      #pragma unroll
      for (int mt = 0; mt < 2; ++mt) {
        long r = row0 + (wv * 2 + mt) * 16 + lcol;
        splitA(xh_ws + r * HH + kt * 32 + lkg * 8, ahi[mt], alo[mt]);
      }
      #pragma unroll
      for (int nt = 0; nt < 8; ++nt) {
        short8v bhi = BFRAG(kt, nt, 0), blo = BFRAG(kt, nt, 1);
        #pragma unroll
        for (int mt = 0; mt < 2; ++mt) {
          acc[mt][nt] = __builtin_amdgcn_mfma_f32_16x16x32_bf16(ahi[mt], bhi, acc[mt][nt], 0, 0, 0);
          acc[mt][nt] = __builtin_amdgcn_mfma_f32_16x16x32_bf16(ahi[mt], blo, acc[mt][nt], 0, 0, 0);
          acc[mt][nt] = __builtin_amdgcn_mfma_f32_16x16x32_bf16(alo[mt], bhi, acc[mt][nt], 0, 0, 0);
        }
      }
    }
    __syncthreads();
    STAGE(3 + mat * 2);
    __syncthreads();
    #pragma unroll
    for (int kt = 0; kt < 4; ++kt) {
      #pragma unroll
      for (int nt = 0; nt < 8; ++nt) {
        short8v bhi = BFRAG(kt, nt, 0), blo = BFRAG(kt, nt, 1);
        #pragma unroll
        for (int mt = 0; mt < 2; ++mt) {
          acc[mt][nt] = __builtin_amdgcn_mfma_f32_16x16x32_bf16(mfr[mt][kt], bhi, acc[mt][nt], 0, 0, 0);
          acc[mt][nt] = __builtin_amdgcn_mfma_f32_16x16x32_bf16(mfr[mt][kt], blo, acc[mt][nt], 0, 0, 0);
        }
      }
    }
    __syncthreads();

    const float* bias = (mat == 0) ? bz : (mat == 1) ? br : bh_;
    #pragma unroll
    for (int mt = 0; mt < 2; ++mt) {
      #pragma unroll
      for (int r = 0; r < 4; ++r) {
        const long g = row0 + (wv * 2 + mt) * 16 + lkg * 4 + r;
        #pragma unroll
        for (int nt = 0; nt < 8; ++nt) {
          const int j = nt * 16 + lcol;
          SB[g * 512 + mat * 128 + j] = acc[mt][nt][r] + bias[j];
        }
      }
    }
  }
  #undef STAGE
  #undef BFRAG
}

// ---------------------------------------------------------------------------
// K3 v4: weights as 96 NAMED SCALARS (no arrays -> no alloca -> no scratch;
// guide rule #20). One memory-clobber asm after the load block makes in-loop
// re-execution of the loads illegal -> values must stay in VGPRs.
// 512 threads = (j, q in 0..3); broadcast LDS gemv; folded gh-decay;
// 4 barriers/step; 2-step SB prefetch (stream-major).
// ---------------------------------------------------------------------------
#define REP32(F) F(0) F(1) F(2) F(3) F(4) F(5) F(6) F(7) \
                 F(8) F(9) F(10) F(11) F(12) F(13) F(14) F(15) \
                 F(16) F(17) F(18) F(19) F(20) F(21) F(22) F(23) \
                 F(24) F(25) F(26) F(27) F(28) F(29) F(30) F(31)

__global__ __launch_bounds__(512) void k3_seq(
    const float* __restrict__ Wz, const float* __restrict__ Wr,
    const float* __restrict__ Wh, const float* __restrict__ SB,
    float* __restrict__ hseq, float* __restrict__ hstate, int TC) {
  const int b = blockIdx.x;
  const int tid = threadIdx.x;
  const int j = tid & (HH - 1);
  const int q = tid >> 7;  // 0..3, wave-uniform
  __shared__ float hdec_s[HH], rh_s[HH];
  __shared__ float pz[4][HH], pr[4][HH], ph[4][HH];

  #define DECLW(i) float wz##i, wr##i, wh##i;
  REP32(DECLW)
  #undef DECLW
  {
    const float* wzp = Wz + (size_t)(HH + 32 * q) * HH + j;
    const float* wrp = Wr + (size_t)(HH + 32 * q) * HH + j;
    const float* whp = Wh + (size_t)(HH + 32 * q) * HH + j;
    #define LOADW(i) wz##i = wzp[(i) * HH]; wr##i = wrp[(i) * HH]; wh##i = whp[(i) * HH];
    REP32(LOADW)
    #undef LOADW
  }
  // Loads may not be re-executed below this point (memory may have changed).
  asm volatile("" ::: "memory");

  float hn = hstate[(size_t)b * HH + j];
  const float* sb = SB + (size_t)b * TC * 512 + j;
  float az0 = sb[0],   ar0 = sb[128], ah0 = sb[256], gh0 = sb[384];
  float az1 = sb[512], ar1 = sb[640], ah1 = sb[768], gh1 = sb[896];
  float hdec = gh0 * hn;
  if (q == 0) hdec_s[j] = hdec;
  __syncthreads();
  for (int tl = 0; tl < TC; ++tl) {
    const int tn = (tl + 2 < TC) ? (tl + 2) : (TC - 1);
    const float* pn = sb + (size_t)tn * 512;
    const float azn = pn[0], arn = pn[128], ahn = pn[256], ghn = pn[384];
    // Phase B: z,r partial gemvs (wave-uniform broadcast reads of hdec_s)
    float za = 0.f, ra = 0.f;
    {
      const float4* hp4 = (const float4*)&hdec_s[32 * q];
      float4 a0 = hp4[0], a1 = hp4[1], a2 = hp4[2], a3 = hp4[3];
      float4 a4 = hp4[4], a5 = hp4[5], a6 = hp4[6], a7 = hp4[7];
      #define QZ(k, i0, i1, i2, i3) \
        za = fmaf(a##k.x, wz##i0, za); ra = fmaf(a##k.x, wr##i0, ra); \
        za = fmaf(a##k.y, wz##i1, za); ra = fmaf(a##k.y, wr##i1, ra); \
        za = fmaf(a##k.z, wz##i2, za); ra = fmaf(a##k.z, wr##i2, ra); \
        za = fmaf(a##k.w, wz##i3, za); ra = fmaf(a##k.w, wr##i3, ra);
      QZ(0, 0, 1, 2, 3)   QZ(1, 4, 5, 6, 7)   QZ(2, 8, 9, 10, 11)
      QZ(3, 12, 13, 14, 15) QZ(4, 16, 17, 18, 19) QZ(5, 20, 21, 22, 23)
      QZ(6, 24, 25, 26, 27) QZ(7, 28, 29, 30, 31)
      #undef QZ
    }
    pz[q][j] = za; pr[q][j] = ra;
    __syncthreads();
    // Phase C: z,r redundant across q; q==0 publishes rh
    float z = sigmoidf_(az0 + ((pz[0][j] + pz[1][j]) + (pz[2][j] + pz[3][j])));
    float r = sigmoidf_(ar0 + ((pr[0][j] + pr[1][j]) + (pr[2][j] + pr[3][j])));
    if (q == 0) rh_s[j] = r * hdec;
    __syncthreads();
    // Phase D: h~ partial gemv
    float ha = 0.f;
    {
      const float4* rp4 = (const float4*)&rh_s[32 * q];
      float4 b0 = rp4[0], b1 = rp4[1], b2 = rp4[2], b3 = rp4[3];
      float4 b4 = rp4[4], b5 = rp4[5], b6 = rp4[6], b7 = rp4[7];
      #define QH(k, i0, i1, i2, i3) \
        ha = fmaf(b##k.x, wh##i0, ha); ha = fmaf(b##k.y, wh##i1, ha); \
        ha = fmaf(b##k.z, wh##i2, ha); ha = fmaf(b##k.w, wh##i3, ha);
      QH(0, 0, 1, 2, 3)   QH(1, 4, 5, 6, 7)   QH(2, 8, 9, 10, 11)
      QH(3, 12, 13, 14, 15) QH(4, 16, 17, 18, 19) QH(5, 20, 21, 22, 23)
      QH(6, 24, 25, 26, 27) QH(7, 28, 29, 30, 31)
      #undef QH
    }
    ph[q][j] = ha;
    __syncthreads();
    // Phase E: h update + fused next-step decay
    float ht = tanhf(ah0 + ((ph[0][j] + ph[1][j]) + (ph[2][j] + ph[3][j])));
    hn = (1.f - z) * hdec + z * ht;
    hdec = gh1 * hn;
    if (q == 0) hdec_s[j] = hdec;
    else if (q == 1) hseq[((size_t)b * TC + tl) * HH + j] = hn;
    __syncthreads();
    az0 = az1; ar0 = ar1; ah0 = ah1; gh0 = gh1;
    az1 = azn; ar1 = arn; ah1 = ahn; gh1 = ghn;
  }
  if (q == 0) hstate[(size_t)b * HH + j] = hn;
}

// ---------------------------------------------------------------------------
// K4: out = hseq_c @ Wo + bo
// ---------------------------------------------------------------------------
__global__ __launch_bounds__(256) void k4_out(
    const float* __restrict__ hseq, const float* __restrict__ Wo,
    const float* __restrict__ bo, float* __restrict__ out,
    int t0, int TC, int l2tc) {
  __shared__ float sH[32][HH];
  const int tid = threadIdx.x;
  const long row0 = (long)blockIdx.x * 32;
  {
    const float4* gh4 = (const float4*)(hseq + row0 * HH);
    float4* sh4 = (float4*)&sH[0][0];
    #pragma unroll
    for (int i = 0; i < 4; ++i) sh4[tid + i * 256] = gh4[tid + i * 256];
  }
  __syncthreads();
  const int tc = tid & 15, tr = tid >> 4;
  const int j0 = tc * 8, r0 = tr * 2;
  float acc[2][8];
  #pragma unroll
  for (int i = 0; i < 2; ++i)
    #pragma unroll
    for (int c = 0; c < 8; ++c) acc[i][c] = 0.f;
  for (int k = 0; k < HH; ++k) {
    float w[8];
    *(float4*)&w[0] = *(const float4*)(Wo + (size_t)k * HH + j0);
    *(float4*)&w[4] = *(const float4*)(Wo + (size_t)k * HH + j0 + 4);
    #pragma unroll
    for (int i = 0; i < 2; ++i) {
      float a = sH[r0 + i][k];
      #pragma unroll
      for (int c = 0; c < 8; ++c) acc[i][c] = fmaf(a, w[c], acc[i][c]);
    }
  }
  #pragma unroll
  for (int i = 0; i < 2; ++i) {
    const long g = row0 + r0 + i;
    const int b = (int)(g >> l2tc);
    const int tloc = (int)(g & (TC - 1));
    #pragma unroll
    for (int c = 0; c < 8; ++c)
      out[((size_t)b * TT + t0 + tloc) * OO + j0 + c] = acc[i][c] + bo[j0 + c];
  }
}

extern "C" void kernel_launch(void* const* d_in, const int* in_sizes, int n_in,
                              void* d_out, int out_size, void* d_ws, size_t ws_size,
                              hipStream_t stream) {
  const float* C    = (const float*)d_in[0];
  const float* tarr = (const float*)d_in[1];
  const float* mask = (const float*)d_in[2];
  const float* Wz   = (const float*)d_in[3];
  const float* bz   = (const float*)d_in[4];
  const float* Wr   = (const float*)d_in[5];
  const float* br   = (const float*)d_in[6];
  const float* Wh   = (const float*)d_in[7];
  const float* bh   = (const float*)d_in[8];
  const float* Wgx  = (const float*)d_in[9];
  const float* bgx  = (const float*)d_in[10];
  const float* Wgh  = (const float*)d_in[11];
  const float* bgh  = (const float*)d_in[12];
  const float* Wo   = (const float*)d_in[13];
  const float* bo   = (const float*)d_in[14];

  int TC = 8, l2tc = 3;
  for (int cand = 1024; cand >= 8; cand >>= 1) {
    size_t need = 524288 +
        ((size_t)6 * BB * HH + (size_t)BB * cand * 1024) * sizeof(float);
    if (need <= ws_size) {
      TC = cand;
      l2tc = 0; while ((1 << l2tc) < cand) ++l2tc;
      break;
    }
  }
  const int NC = TT / TC;

  short* WFRAG = (short*)d_ws;
  float* fbase = (float*)((char*)d_ws + 524288);
  const size_t BH = (size_t)BB * HH;
  float* xmean    = fbase;
  float* carry    = xmean + BH;
  float* hstate   = carry + 4 * BH;
  float* delta_c  = hstate + BH;
  float* xlastp_c = delta_c + (size_t)BB * TC * HH;
  float* SB_c     = xlastp_c + (size_t)BB * TC * HH;
  float* hseq_c   = SB_c + (size_t)BB * TC * 512;
  float* xh_ws    = hseq_c + (size_t)BB * TC * HH;

  k0_wprep<<<8, 256, 0, stream>>>(Wz, Wr, Wh, Wgx, Wgh, WFRAG);
  k1a_mean<<<BB, 512, 0, stream>>>(C, mask, xmean, carry, hstate);
  for (int c = 0; c < NC; ++c) {
    const int t0 = c * TC;
    k1b_scan<<<BB, 128, 0, stream>>>(C, tarr, mask, carry, delta_c, xlastp_c, t0, TC);
    k2_mfma<<<BB * TC / 128, 256, 0, stream>>>(C, mask, bz, br, bh, bgx, bgh,
                                               xmean, delta_c, xlastp_c,
                                               WFRAG, xh_ws, SB_c, t0, TC, l2tc);
    k3_seq<<<BB, 512, 0, stream>>>(Wz, Wr, Wh, SB_c, hseq_c, hstate, TC);
    k4_out<<<BB * TC / 32, 256, 0, stream>>>(hseq_c, Wo, bo, (float*)d_out, t0, TC, l2tc);
  }
}

// Round 10
// 2659.190 us; speedup vs baseline: 1.0576x; 1.0576x over previous
//
#include <hip/hip_runtime.h>
#include <hip/hip_bf16.h>
#include <cstdint>

#define BB 256
#define TT 1024
#define HH 128
#define OO 128

typedef __attribute__((ext_vector_type(8))) short short8v;
typedef __attribute__((ext_vector_type(4))) float f32x4;

#define LOG2E 1.4426950408889634f

__device__ __forceinline__ float fast_sigmoid(float x) {
  float e = __builtin_amdgcn_exp2f(-LOG2E * x);
  return __builtin_amdgcn_rcpf(1.f + e);
}
__device__ __forceinline__ float fast_tanh(float x) {
  float e = __builtin_amdgcn_exp2f((2.f * LOG2E) * x);
  return 1.f - 2.f * __builtin_amdgcn_rcpf(1.f + e);
}
__device__ __forceinline__ float fast_expneg(float x) {  // exp(-max(x,0))
  return __builtin_amdgcn_exp2f(-LOG2E * fmaxf(x, 0.f));
}

__device__ __forceinline__ short f2bf(float x) {
  unsigned u = __float_as_uint(x);
  u = u + 0x7fffu + ((u >> 16) & 1u);
  return (short)(u >> 16);
}
__device__ __forceinline__ float bf2f(short s) {
  return __uint_as_float(((unsigned)(unsigned short)s) << 16);
}
__device__ __forceinline__ void splitA(const float* p, short8v& hi, short8v& lo) {
  float4 a = *(const float4*)p;
  float4 b = *(const float4*)(p + 4);
  float v[8] = {a.x, a.y, a.z, a.w, b.x, b.y, b.z, b.w};
  #pragma unroll
  for (int i = 0; i < 8; ++i) {
    short h = f2bf(v[i]);
    hi[i] = h;
    lo[i] = f2bf(v[i] - bf2f(h));
  }
}

// ---------------------------------------------------------------------------
// K0: weight prep -> hi/lo bf16 MFMA-B fragment-linear layout.
// mats: 0=Wgx 1=Wgh 2=Wz1 3=Wz3 4=Wr1 5=Wr3 6=Wh1 7=Wh3
// ---------------------------------------------------------------------------
__global__ __launch_bounds__(256) void k0_wprep(
    const float* __restrict__ Wz, const float* __restrict__ Wr,
    const float* __restrict__ Wh, const float* __restrict__ Wgx,
    const float* __restrict__ Wgh, short* __restrict__ WFRAG) {
  const int mat = blockIdx.x;
  const float* src;
  int koff;
  switch (mat) {
    case 0: src = Wgx; koff = 0; break;
    case 1: src = Wgh; koff = 0; break;
    case 2: src = Wz;  koff = 0; break;
    case 3: src = Wz;  koff = 256; break;
    case 4: src = Wr;  koff = 0; break;
    case 5: src = Wr;  koff = 256; break;
    case 6: src = Wh;  koff = 0; break;
    default: src = Wh; koff = 256; break;
  }
  short* hi = WFRAG + (size_t)mat * 32768;
  short* lo = hi + 16384;
  for (int e = threadIdx.x; e < 16384; e += 256) {
    int i = e & 7, ln = (e >> 3) & 63, tile = e >> 9;
    int kt = tile >> 3, nt = tile & 7;
    int k = kt * 32 + (ln >> 4) * 8 + i;
    int n = nt * 16 + (ln & 15);
    float w = src[(size_t)(koff + k) * HH + n];
    short h = f2bf(w);
    hi[e] = h;
    lo[e] = f2bf(w - bf2f(h));
  }
}

// ---------------------------------------------------------------------------
// K1a: x_mean + init carry/hstate. carry: 0=xlast 1=delta_prev 2=tprev 3=m_prev
// ---------------------------------------------------------------------------
__global__ __launch_bounds__(512) void k1a_mean(
    const float* __restrict__ C, const float* __restrict__ mask,
    float* __restrict__ xmean, float* __restrict__ carry,
    float* __restrict__ hstate) {
  const int b = blockIdx.x;
  const int h = threadIdx.x & (HH - 1);
  const int s = threadIdx.x >> 7;
  __shared__ float ssum[4][HH], scnt[4][HH];
  const float* mptr = mask + (size_t)b * TT * HH + h;
  float sum = 0.f, cnt = 0.f;
  for (int t = s; t < TT; t += 4) {
    float m = mptr[(size_t)t * HH];
    sum = fmaf(m, C[t * HH + h], sum);
    cnt += m;
  }
  ssum[s][h] = sum; scnt[s][h] = cnt;
  __syncthreads();
  if (s == 0) {
    float S = (ssum[0][h] + ssum[1][h]) + (ssum[2][h] + ssum[3][h]);
    float N = (scnt[0][h] + scnt[1][h]) + (scnt[2][h] + scnt[3][h]);
    float xm = S / fmaxf(N, 1.f);
    const size_t bh = (size_t)b * HH + h;
    const size_t BH = (size_t)BB * HH;
    xmean[bh] = xm;
    carry[0 * BH + bh] = xm;
    carry[1 * BH + bh] = 0.f;
    carry[2 * BH + bh] = 0.f;
    carry[3 * BH + bh] = 1.f;
    hstate[bh] = 0.f;
  }
}

// ---------------------------------------------------------------------------
// K1b: per-(b,h) scan for one chunk -> delta_c, xlastp_c
// ---------------------------------------------------------------------------
__global__ __launch_bounds__(128) void k1b_scan(
    const float* __restrict__ C, const float* __restrict__ tarr,
    const float* __restrict__ mask, float* __restrict__ carry,
    float* __restrict__ delta_c, float* __restrict__ xlastp_c,
    int t0, int TC) {
  const int b = blockIdx.x;
  const int h = threadIdx.x;
  const size_t bh = (size_t)b * HH + h;
  const size_t BH = (size_t)BB * HH;
  float xl = carry[0 * BH + bh];
  float dp = carry[1 * BH + bh];
  float tprev = carry[2 * BH + bh];
  float mp = carry[3 * BH + bh];
  const float* trow = tarr + (size_t)b * TT;
  const float* mptr = mask + ((size_t)b * TT + t0) * HH + h;
  const size_t cbase = (size_t)b * TC * HH + h;
  for (int tl = 0; tl < TC; ++tl) {
    const int t = t0 + tl;
    float tc = trow[t];
    float dt = (t == 0) ? 0.f : (tc - tprev);
    float d = dt + (1.f - mp) * dp;
    delta_c[cbase + (size_t)tl * HH] = d;
    xlastp_c[cbase + (size_t)tl * HH] = xl;
    float m = mptr[(size_t)tl * HH];
    float xv = C[t * HH + h];
    xl = m * xv + (1.f - m) * xl;
    mp = m; dp = d; tprev = tc;
  }
  carry[0 * BH + bh] = xl;
  carry[1 * BH + bh] = dp;
  carry[2 * BH + bh] = tprev;
  carry[3 * BH + bh] = mp;
}

// ---------------------------------------------------------------------------
// K2: split-bf16 MFMA precompute. SB stream-major:
// SB[g][s][128], s: 0=az 1=ar 2=ah 3=gh.
// ---------------------------------------------------------------------------
__global__ __launch_bounds__(256) void k2_mfma(
    const float* __restrict__ C, const float* __restrict__ mask,
    const float* __restrict__ bz, const float* __restrict__ br,
    const float* __restrict__ bh_, const float* __restrict__ bgx,
    const float* __restrict__ bgh, const float* __restrict__ xmean,
    const float* __restrict__ delta, const float* __restrict__ xlastp,
    const short* __restrict__ WFRAG, float* __restrict__ xh_ws,
    float* __restrict__ SB, int t0, int TC, int l2tc) {
  __shared__ short sW[32768];
  const int tid = threadIdx.x;
  const int lane = tid & 63;
  const int wv = tid >> 6;
  const long row0 = (long)blockIdx.x * 128;
  const int lcol = lane & 15;
  const int lkg = lane >> 4;

  #define STAGE(matIdx)                                                      \
    {                                                                        \
      const int4* gsrc = (const int4*)(WFRAG + (size_t)(matIdx) * 32768);    \
      int4* gdst = (int4*)sW;                                                \
      _Pragma("unroll")                                                      \
      for (int i_ = 0; i_ < 16; ++i_) gdst[tid + i_ * 256] = gsrc[tid + i_ * 256]; \
    }
  #define BFRAG(kt, nt, plane) \
    (*(const short8v*)&sW[(plane) * 16384 + (((kt) * 8 + (nt)) * 64 + lane) * 8])

  // ================= Phase A =================
  f32x4 accGX[2][8], accGH[2][8];
  const f32x4 zero4 = {0.f, 0.f, 0.f, 0.f};
  #pragma unroll
  for (int mt = 0; mt < 2; ++mt)
    #pragma unroll
    for (int nt = 0; nt < 8; ++nt) { accGX[mt][nt] = zero4; accGH[mt][nt] = zero4; }

  STAGE(0);
  __syncthreads();
  #pragma unroll
  for (int kt = 0; kt < 4; ++kt) {
    short8v ahi[2], alo[2];
    #pragma unroll
    for (int mt = 0; mt < 2; ++mt) {
      long r = row0 + (wv * 2 + mt) * 16 + lcol;
      splitA(delta + r * HH + kt * 32 + lkg * 8, ahi[mt], alo[mt]);
    }
    #pragma unroll
    for (int nt = 0; nt < 8; ++nt) {
      short8v bhi = BFRAG(kt, nt, 0), blo = BFRAG(kt, nt, 1);
      #pragma unroll
      for (int mt = 0; mt < 2; ++mt) {
        accGX[mt][nt] = __builtin_amdgcn_mfma_f32_16x16x32_bf16(ahi[mt], bhi, accGX[mt][nt], 0, 0, 0);
        accGX[mt][nt] = __builtin_amdgcn_mfma_f32_16x16x32_bf16(ahi[mt], blo, accGX[mt][nt], 0, 0, 0);
        accGX[mt][nt] = __builtin_amdgcn_mfma_f32_16x16x32_bf16(alo[mt], bhi, accGX[mt][nt], 0, 0, 0);
      }
    }
  }
  __syncthreads();
  STAGE(1);
  __syncthreads();
  #pragma unroll
  for (int kt = 0; kt < 4; ++kt) {
    short8v ahi[2], alo[2];
    #pragma unroll
    for (int mt = 0; mt < 2; ++mt) {
      long r = row0 + (wv * 2 + mt) * 16 + lcol;
      splitA(delta + r * HH + kt * 32 + lkg * 8, ahi[mt], alo[mt]);
    }
    #pragma unroll
    for (int nt = 0; nt < 8; ++nt) {
      short8v bhi = BFRAG(kt, nt, 0), blo = BFRAG(kt, nt, 1);
      #pragma unroll
      for (int mt = 0; mt < 2; ++mt) {
        accGH[mt][nt] = __builtin_amdgcn_mfma_f32_16x16x32_bf16(ahi[mt], bhi, accGH[mt][nt], 0, 0, 0);
        accGH[mt][nt] = __builtin_amdgcn_mfma_f32_16x16x32_bf16(ahi[mt], blo, accGH[mt][nt], 0, 0, 0);
        accGH[mt][nt] = __builtin_amdgcn_mfma_f32_16x16x32_bf16(alo[mt], bhi, accGH[mt][nt], 0, 0, 0);
      }
    }
  }
  __syncthreads();

  #pragma unroll
  for (int mt = 0; mt < 2; ++mt) {
    #pragma unroll
    for (int r = 0; r < 4; ++r) {
      const int mrow = (wv * 2 + mt) * 16 + lkg * 4 + r;
      const long g = row0 + mrow;
      const int b = (int)(g >> l2tc);
      const int tl = (int)(g & (TC - 1));
      const int tg = t0 + tl;
      #pragma unroll
      for (int nt = 0; nt < 8; ++nt) {
        const int j = nt * 16 + lcol;
        float gx = fast_expneg(accGX[mt][nt][r] + bgx[j]);
        float gh = fast_expneg(accGH[mt][nt][r] + bgh[j]);
        SB[g * 512 + 384 + j] = gh;
        float mk = mask[((size_t)b * TT + tg) * HH + j];
        float xl = xlastp[g * HH + j];
        float xmn = xmean[(size_t)b * HH + j];
        float xv = C[(size_t)tg * HH + j];
        xh_ws[g * HH + j] = mk * xv + (1.f - mk) * (gx * xl + (1.f - gx) * xmn);
      }
    }
  }
  __threadfence_block();
  __syncthreads();

  // ================= Phase B =================
  short8v mfr[2][4];
  #pragma unroll
  for (int mt = 0; mt < 2; ++mt) {
    long r = row0 + (wv * 2 + mt) * 16 + lcol;
    const int b = (int)(r >> l2tc);
    const int tl = (int)(r & (TC - 1));
    const float* mrow = mask + ((size_t)b * TT + t0 + tl) * HH;
    #pragma unroll
    for (int kt = 0; kt < 4; ++kt) {
      float4 p = *(const float4*)(mrow + kt * 32 + lkg * 8);
      float4 q = *(const float4*)(mrow + kt * 32 + lkg * 8 + 4);
      float v[8] = {p.x, p.y, p.z, p.w, q.x, q.y, q.z, q.w};
      #pragma unroll
      for (int i = 0; i < 8; ++i) mfr[mt][kt][i] = f2bf(v[i]);
    }
  }

  #pragma unroll 1
  for (int mat = 0; mat < 3; ++mat) {
    f32x4 acc[2][8];
    #pragma unroll
    for (int mt = 0; mt < 2; ++mt)
      #pragma unroll
      for (int nt = 0; nt < 8; ++nt) acc[mt][nt] = zero4;

    STAGE(2 + mat * 2);
    __syncthreads();
    #pragma unroll
    for (int kt = 0; kt < 4; ++kt) {
      short8v ahi[2], alo[2];
      #pragma unroll
      for (int mt = 0; mt < 2; ++mt) {
        long r = row0 + (wv * 2 + mt) * 16 + lcol;
        splitA(xh_ws + r * HH + kt * 32 + lkg * 8, ahi[mt], alo[mt]);
      }
      #pragma unroll
      for (int nt = 0; nt < 8; ++nt) {
        short8v bhi = BFRAG(kt, nt, 0), blo = BFRAG(kt, nt, 1);
        #pragma unroll
        for (int mt = 0; mt < 2; ++mt) {
          acc[mt][nt] = __builtin_amdgcn_mfma_f32_16x16x32_bf16(ahi[mt], bhi, acc[mt][nt], 0, 0, 0);
          acc[mt][nt] = __builtin_amdgcn_mfma_f32_16x16x32_bf16(ahi[mt], blo, acc[mt][nt], 0, 0, 0);
          acc[mt][nt] = __builtin_amdgcn_mfma_f32_16x16x32_bf16(alo[mt], bhi, acc[mt][nt], 0, 0, 0);
        }
      }
    }
    __syncthreads();
    STAGE(3 + mat * 2);
    __syncthreads();
    #pragma unroll
    for (int kt = 0; kt < 4; ++kt) {
      #pragma unroll
      for (int nt = 0; nt < 8; ++nt) {
        short8v bhi = BFRAG(kt, nt, 0), blo = BFRAG(kt, nt, 1);
        #pragma unroll
        for (int mt = 0; mt < 2; ++mt) {
          acc[mt][nt] = __builtin_amdgcn_mfma_f32_16x16x32_bf16(mfr[mt][kt], bhi, acc[mt][nt], 0, 0, 0);
          acc[mt][nt] = __builtin_amdgcn_mfma_f32_16x16x32_bf16(mfr[mt][kt], blo, acc[mt][nt], 0, 0, 0);
        }
      }
    }
    __syncthreads();

    const float* bias = (mat == 0) ? bz : (mat == 1) ? br : bh_;
    #pragma unroll
    for (int mt = 0; mt < 2; ++mt) {
      #pragma unroll
      for (int r = 0; r < 4; ++r) {
        const long g = row0 + (wv * 2 + mt) * 16 + lkg * 4 + r;
        #pragma unroll
        for (int nt = 0; nt < 8; ++nt) {
          const int j = nt * 16 + lcol;
          SB[g * 512 + mat * 128 + j] = acc[mt][nt][r] + bias[j];
        }
      }
    }
  }
  #undef STAGE
  #undef BFRAG
}

// ---------------------------------------------------------------------------
// K3 v5: named-scalar weights + amdgpu_waves_per_eu(2,2) (pins backend
// occupancy target at 2 waves/EU -> 256-VGPR budget, so the scheduler has
// no incentive to spill the 96 weight regs) + call-free exp2 transcendentals
// + 2-way split accumulator chains. Same phase structure as v4.
// ---------------------------------------------------------------------------
#define REP32(F) F(0) F(1) F(2) F(3) F(4) F(5) F(6) F(7) \
                 F(8) F(9) F(10) F(11) F(12) F(13) F(14) F(15) \
                 F(16) F(17) F(18) F(19) F(20) F(21) F(22) F(23) \
                 F(24) F(25) F(26) F(27) F(28) F(29) F(30) F(31)

__global__ __launch_bounds__(512)
__attribute__((amdgpu_waves_per_eu(2, 2)))
void k3_seq(
    const float* __restrict__ Wz, const float* __restrict__ Wr,
    const float* __restrict__ Wh, const float* __restrict__ SB,
    float* __restrict__ hseq, float* __restrict__ hstate, int TC) {
  const int b = blockIdx.x;
  const int tid = threadIdx.x;
  const int j = tid & (HH - 1);
  const int q = tid >> 7;  // 0..3, wave-uniform
  __shared__ float hdec_s[HH], rh_s[HH];
  __shared__ float pz[4][HH], pr[4][HH], ph[4][HH];

  #define DECLW(i) float wz##i, wr##i, wh##i;
  REP32(DECLW)
  #undef DECLW
  {
    const float* wzp = Wz + (size_t)(HH + 32 * q) * HH + j;
    const float* wrp = Wr + (size_t)(HH + 32 * q) * HH + j;
    const float* whp = Wh + (size_t)(HH + 32 * q) * HH + j;
    #define LOADW(i) wz##i = wzp[(i) * HH]; wr##i = wrp[(i) * HH]; wh##i = whp[(i) * HH];
    REP32(LOADW)
    #undef LOADW
  }
  // Loads may not be re-executed below this point (memory may have changed).
  asm volatile("" ::: "memory");

  float hn = hstate[(size_t)b * HH + j];
  const float* sb = SB + (size_t)b * TC * 512 + j;
  float az0 = sb[0],   ar0 = sb[128], ah0 = sb[256], gh0 = sb[384];
  float az1 = sb[512], ar1 = sb[640], ah1 = sb[768], gh1 = sb[896];
  float hdec = gh0 * hn;
  if (q == 0) hdec_s[j] = hdec;
  __syncthreads();
  for (int tl = 0; tl < TC; ++tl) {
    const int tn = (tl + 2 < TC) ? (tl + 2) : (TC - 1);
    const float* pn = sb + (size_t)tn * 512;
    const float azn = pn[0], arn = pn[128], ahn = pn[256], ghn = pn[384];
    // Phase B: z,r partial gemvs (wave-uniform broadcast reads of hdec_s)
    float zacc0 = 0.f, zacc1 = 0.f, racc0 = 0.f, racc1 = 0.f;
    {
      const float4* hp4 = (const float4*)&hdec_s[32 * q];
      float4 a0 = hp4[0], a1 = hp4[1], a2 = hp4[2], a3 = hp4[3];
      float4 a4 = hp4[4], a5 = hp4[5], a6 = hp4[6], a7 = hp4[7];
      #define QZ(k, s, i0, i1, i2, i3) \
        zacc##s = fmaf(a##k.x, wz##i0, zacc##s); racc##s = fmaf(a##k.x, wr##i0, racc##s); \
        zacc##s = fmaf(a##k.y, wz##i1, zacc##s); racc##s = fmaf(a##k.y, wr##i1, racc##s); \
        zacc##s = fmaf(a##k.z, wz##i2, zacc##s); racc##s = fmaf(a##k.z, wr##i2, racc##s); \
        zacc##s = fmaf(a##k.w, wz##i3, zacc##s); racc##s = fmaf(a##k.w, wr##i3, racc##s);
      QZ(0, 0, 0, 1, 2, 3)    QZ(1, 1, 4, 5, 6, 7)
      QZ(2, 0, 8, 9, 10, 11)  QZ(3, 1, 12, 13, 14, 15)
      QZ(4, 0, 16, 17, 18, 19) QZ(5, 1, 20, 21, 22, 23)
      QZ(6, 0, 24, 25, 26, 27) QZ(7, 1, 28, 29, 30, 31)
      #undef QZ
    }
    pz[q][j] = zacc0 + zacc1; pr[q][j] = racc0 + racc1;
    __syncthreads();
    // Phase C: z,r redundant across q; q==0 publishes rh
    float z = fast_sigmoid(az0 + ((pz[0][j] + pz[1][j]) + (pz[2][j] + pz[3][j])));
    float r = fast_sigmoid(ar0 + ((pr[0][j] + pr[1][j]) + (pr[2][j] + pr[3][j])));
    if (q == 0) rh_s[j] = r * hdec;
    __syncthreads();
    // Phase D: h~ partial gemv
    float hacc0 = 0.f, hacc1 = 0.f;
    {
      const float4* rp4 = (const float4*)&rh_s[32 * q];
      float4 b0 = rp4[0], b1 = rp4[1], b2 = rp4[2], b3 = rp4[3];
      float4 b4 = rp4[4], b5 = rp4[5], b6 = rp4[6], b7 = rp4[7];
      #define QH(k, s, i0, i1, i2, i3) \
        hacc##s = fmaf(b##k.x, wh##i0, hacc##s); hacc##s = fmaf(b##k.y, wh##i1, hacc##s); \
        hacc##s = fmaf(b##k.z, wh##i2, hacc##s); hacc##s = fmaf(b##k.w, wh##i3, hacc##s);
      QH(0, 0, 0, 1, 2, 3)    QH(1, 1, 4, 5, 6, 7)
      QH(2, 0, 8, 9, 10, 11)  QH(3, 1, 12, 13, 14, 15)
      QH(4, 0, 16, 17, 18, 19) QH(5, 1, 20, 21, 22, 23)
      QH(6, 0, 24, 25, 26, 27) QH(7, 1, 28, 29, 30, 31)
      #undef QH
    }
    ph[q][j] = hacc0 + hacc1;
    __syncthreads();
    // Phase E: h update + fused next-step decay
    float ht = fast_tanh(ah0 + ((ph[0][j] + ph[1][j]) + (ph[2][j] + ph[3][j])));
    hn = (1.f - z) * hdec + z * ht;
    hdec = gh1 * hn;
    if (q == 0) hdec_s[j] = hdec;
    else if (q == 1) hseq[((size_t)b * TC + tl) * HH + j] = hn;
    __syncthreads();
    az0 = az1; ar0 = ar1; ah0 = ah1; gh0 = gh1;
    az1 = azn; ar1 = arn; ah1 = ahn; gh1 = ghn;
  }
  if (q == 0) hstate[(size_t)b * HH + j] = hn;
}

// ---------------------------------------------------------------------------
// K4: out = hseq_c @ Wo + bo
// ---------------------------------------------------------------------------
__global__ __launch_bounds__(256) void k4_out(
    const float* __restrict__ hseq, const float* __restrict__ Wo,
    const float* __restrict__ bo, float* __restrict__ out,
    int t0, int TC, int l2tc) {
  __shared__ float sH[32][HH];
  const int tid = threadIdx.x;
  const long row0 = (long)blockIdx.x * 32;
  {
    const float4* gh4 = (const float4*)(hseq + row0 * HH);
    float4* sh4 = (float4*)&sH[0][0];
    #pragma unroll
    for (int i = 0; i < 4; ++i) sh4[tid + i * 256] = gh4[tid + i * 256];
  }
  __syncthreads();
  const int tc = tid & 15, tr = tid >> 4;
  const int j0 = tc * 8, r0 = tr * 2;
  float acc[2][8];
  #pragma unroll
  for (int i = 0; i < 2; ++i)
    #pragma unroll
    for (int c = 0; c < 8; ++c) acc[i][c] = 0.f;
  for (int k = 0; k < HH; ++k) {
    float w[8];
    *(float4*)&w[0] = *(const float4*)(Wo + (size_t)k * HH + j0);
    *(float4*)&w[4] = *(const float4*)(Wo + (size_t)k * HH + j0 + 4);
    #pragma unroll
    for (int i = 0; i < 2; ++i) {
      float a = sH[r0 + i][k];
      #pragma unroll
      for (int c = 0; c < 8; ++c) acc[i][c] = fmaf(a, w[c], acc[i][c]);
    }
  }
  #pragma unroll
  for (int i = 0; i < 2; ++i) {
    const long g = row0 + r0 + i;
    const int b = (int)(g >> l2tc);
    const int tloc = (int)(g & (TC - 1));
    #pragma unroll
    for (int c = 0; c < 8; ++c)
      out[((size_t)b * TT + t0 + tloc) * OO + j0 + c] = acc[i][c] + bo[j0 + c];
  }
}

extern "C" void kernel_launch(void* const* d_in, const int* in_sizes, int n_in,
                              void* d_out, int out_size, void* d_ws, size_t ws_size,
                              hipStream_t stream) {
  const float* C    = (const float*)d_in[0];
  const float* tarr = (const float*)d_in[1];
  const float* mask = (const float*)d_in[2];
  const float* Wz   = (const float*)d_in[3];
  const float* bz   = (const float*)d_in[4];
  const float* Wr   = (const float*)d_in[5];
  const float* br   = (const float*)d_in[6];
  const float* Wh   = (const float*)d_in[7];
  const float* bh   = (const float*)d_in[8];
  const float* Wgx  = (const float*)d_in[9];
  const float* bgx  = (const float*)d_in[10];
  const float* Wgh  = (const float*)d_in[11];
  const float* bgh  = (const float*)d_in[12];
  const float* Wo   = (const float*)d_in[13];
  const float* bo   = (const float*)d_in[14];

  int TC = 8, l2tc = 3;
  for (int cand = 1024; cand >= 8; cand >>= 1) {
    size_t need = 524288 +
        ((size_t)6 * BB * HH + (size_t)BB * cand * 1024) * sizeof(float);
    if (need <= ws_size) {
      TC = cand;
      l2tc = 0; while ((1 << l2tc) < cand) ++l2tc;
      break;
    }
  }
  const int NC = TT / TC;

  short* WFRAG = (short*)d_ws;
  float* fbase = (float*)((char*)d_ws + 524288);
  const size_t BH = (size_t)BB * HH;
  float* xmean    = fbase;
  float* carry    = xmean + BH;
  float* hstate   = carry + 4 * BH;
  float* delta_c  = hstate + BH;
  float* xlastp_c = delta_c + (size_t)BB * TC * HH;
  float* SB_c     = xlastp_c + (size_t)BB * TC * HH;
  float* hseq_c   = SB_c + (size_t)BB * TC * 512;
  float* xh_ws    = hseq_c + (size_t)BB * TC * HH;

  k0_wprep<<<8, 256, 0, stream>>>(Wz, Wr, Wh, Wgx, Wgh, WFRAG);
  k1a_mean<<<BB, 512, 0, stream>>>(C, mask, xmean, carry, hstate);
  for (int c = 0; c < NC; ++c) {
    const int t0 = c * TC;
    k1b_scan<<<BB, 128, 0, stream>>>(C, tarr, mask, carry, delta_c, xlastp_c, t0, TC);
    k2_mfma<<<BB * TC / 128, 256, 0, stream>>>(C, mask, bz, br, bh, bgx, bgh,
                                               xmean, delta_c, xlastp_c,
                                               WFRAG, xh_ws, SB_c, t0, TC, l2tc);
    k3_seq<<<BB, 512, 0, stream>>>(Wz, Wr, Wh, SB_c, hseq_c, hstate, TC);
    k4_out<<<BB * TC / 32, 256, 0, stream>>>(hseq_c, Wo, bo, (float*)d_out, t0, TC, l2tc);
  }
}